// Round 4
// baseline (579.110 us; speedup 1.0000x reference)
//
#include <hip/hip_runtime.h>

#define N_NODES 200000
#define DIM 480            // 120 float4 per row
#define N_SEG 4096
#define VEC (DIM / 4)      // 120
#define CHUNK 8            // rows in flight per wave in gather
#define HIST_BLOCK 256
#define HIST_GRID ((N_NODES + HIST_BLOCK - 1) / HIST_BLOCK)

// 1) histogram (full GPU, global atomics over 4096 bins) + "last block
//    finishes -> scan" fusion. done-counter and counts zeroed by one memset.
__global__ __launch_bounds__(HIST_BLOCK) void hist_scan_kernel(
    const int* __restrict__ labels,
    int* __restrict__ counts,     // [N_SEG], pre-zeroed
    int* __restrict__ done,       // [1], pre-zeroed
    int* __restrict__ cursor) {   // [N_SEG] out: exclusive prefix
    int i = blockIdx.x * blockDim.x + threadIdx.x;
    if (i < N_NODES) atomicAdd(&counts[labels[i]], 1);
    __threadfence();              // make this block's adds visible device-wide

    __shared__ int is_last;
    if (threadIdx.x == 0) {
        int old = atomicAdd(done, 1);
        is_last = (old == (int)gridDim.x - 1);
    }
    __syncthreads();
    if (!is_last) return;

    // This block observed all other blocks' atomics (done-counter ordering).
    // Read counts through the atomic path to stay coherent across XCDs.
    __shared__ int part[HIST_BLOCK];
    int t = threadIdx.x;
    int local[16];
    int base = t * 16;
    int sum = 0;
#pragma unroll
    for (int k = 0; k < 16; ++k) {
        local[k] = atomicAdd(&counts[base + k], 0);   // coherent read
        sum += local[k];
    }
    part[t] = sum;
    __syncthreads();
    for (int off = 1; off < HIST_BLOCK; off <<= 1) {
        int add = (t >= off) ? part[t - off] : 0;
        __syncthreads();
        part[t] += add;
        __syncthreads();
    }
    int excl = (t == 0) ? 0 : part[t - 1];
#pragma unroll
    for (int k = 0; k < 16; ++k) { cursor[base + k] = excl; excl += local[k]; }
}

// 2) counting-sort scatter: sorted_idx[pos] = node index
//    afterwards cursor[s] == segment end offset
__global__ void scatter_kernel(const int* __restrict__ labels,
                               int* __restrict__ cursor,
                               int* __restrict__ sorted_idx, int n) {
    int i = blockIdx.x * blockDim.x + threadIdx.x;
    if (i < n) {
        int pos = atomicAdd(&cursor[labels[i]], 1);
        sorted_idx[pos] = i;
    }
}

// 3) per-segment gather + mean, 8 rows in flight per iteration (R2-proven).
__global__ __launch_bounds__(128) void gather_mean_kernel(
    const float* __restrict__ x,
    const int* __restrict__ sorted_idx,
    const int* __restrict__ counts,
    const int* __restrict__ cursor,
    float* __restrict__ out) {
    int s = blockIdx.x;
    int cnt = counts[s];
    int end = cursor[s];
    int start = end - cnt;
    int t = threadIdx.x;
    if (t >= VEC) return;

    float4 acc = make_float4(0.f, 0.f, 0.f, 0.f);
    if (cnt > 0) {
        for (int j = start; j < end; j += CHUNK) {
            int   idx[CHUNK];
            float w[CHUNK];
#pragma unroll
            for (int k = 0; k < CHUNK; ++k) {
                int jj = j + k;
                w[k]   = (jj < end) ? 1.0f : 0.0f;
                idx[k] = sorted_idx[(jj < end) ? jj : start];
            }
            float4 v[CHUNK];
#pragma unroll
            for (int k = 0; k < CHUNK; ++k) {
                const float4* row = (const float4*)(x + (size_t)idx[k] * DIM);
                v[k] = row[t];
            }
#pragma unroll
            for (int k = 0; k < CHUNK; ++k) {
                acc.x = fmaf(w[k], v[k].x, acc.x);
                acc.y = fmaf(w[k], v[k].y, acc.y);
                acc.z = fmaf(w[k], v[k].z, acc.z);
                acc.w = fmaf(w[k], v[k].w, acc.w);
            }
        }
    }
    float inv = (cnt > 0) ? (1.0f / (float)cnt) : 0.0f;
    float4 r = make_float4(acc.x * inv, acc.y * inv, acc.z * inv, acc.w * inv);
    ((float4*)(out + (size_t)s * DIM))[t] = r;
}

extern "C" void kernel_launch(void* const* d_in, const int* in_sizes, int n_in,
                              void* d_out, int out_size, void* d_ws, size_t ws_size,
                              hipStream_t stream) {
    const float* x      = (const float*)d_in[0];
    const int*   labels = (const int*)d_in[1];
    float* out = (float*)d_out;

    // workspace layout: counts[4096] | done[1] | pad[3] | cursor[4096] | sorted_idx[200000]
    int* counts     = (int*)d_ws;
    int* done       = counts + N_SEG;
    int* cursor     = done + 4;
    int* sorted_idx = cursor + N_SEG;

    // zero counts + done in one memset (16 KB + 16 B)
    hipMemsetAsync(counts, 0, (N_SEG + 4) * sizeof(int), stream);

    hist_scan_kernel<<<HIST_GRID, HIST_BLOCK, 0, stream>>>(labels, counts, done, cursor);
    scatter_kernel<<<(N_NODES + 255) / 256, 256, 0, stream>>>(labels, cursor,
                                                              sorted_idx, N_NODES);
    gather_mean_kernel<<<N_SEG, 128, 0, stream>>>(x, sorted_idx, counts, cursor, out);
}